// Round 1
// baseline (42.063 us; speedup 1.0000x reference)
//
#include <hip/hip_runtime.h>
#include <math.h>

#define BB 64
#define LL 512
#define DD 768
#define HH 768
#define KK 128

__global__ __launch_bounds__(768) void halton_fused_kernel(
    const float* __restrict__ enc,        // (B, L, D)
    const float* __restrict__ W1,         // (D, H) row-major
    const float* __restrict__ b1,         // (H)
    const float* __restrict__ W2,         // (H, K) row-major
    const float* __restrict__ b2,         // (K)
    const int*   __restrict__ valid_mask, // (B, L)
    const int*   __restrict__ pos_span,   // (B, 2)
    float*       __restrict__ out)        // (B, K)
{
    __shared__ int   s_idx[40];   // indices of valid ranks 0..39
    __shared__ int   s_count;
    __shared__ float s_feat[DD];
    __shared__ float s_h[HH];

    const int b   = blockIdx.x;
    const int tid = threadIdx.x;
    const int lo  = pos_span[b * 2 + 0];
    const int hi  = pos_span[b * 2 + 1];   // hi <= 39 by construction

    // ---- Phase 0: wave-0 ballot scan of valid_mask row -> compacted indices
    if (tid < 64) {
        int count = 0;
        #pragma unroll
        for (int c = 0; c < LL / 64; ++c) {
            int l = c * 64 + tid;
            int v = valid_mask[b * LL + l];
            unsigned long long m = __ballot(v == 1);
            if (v == 1) {
                int rank = count + __popcll(m & ((1ull << tid) - 1ull));
                if (rank < 40) s_idx[rank] = l;
            }
            count += __popcll(m);
        }
        if (tid == 0) s_count = count;
    }
    __syncthreads();
    const int count = s_count;

    // ---- Phase 1: feat[d] = max over span positions (zero rows where p >= count)
    {
        float m = -INFINITY;
        const int pend = min(hi, count - 1);
        for (int p = lo; p <= pend; ++p) {
            m = fmaxf(m, enc[((long)b * LL + s_idx[p]) * DD + tid]);
        }
        if (hi >= count) m = fmaxf(m, 0.0f);  // at least one zero row in span
        s_feat[tid] = m;
    }
    __syncthreads();

    // ---- Phase 2: h[j] = relu(feat . W1[:,j] + b1[j]), one thread per column
    {
        float acc = b1[tid];
        #pragma unroll 8
        for (int k = 0; k < DD; ++k) {
            acc += s_feat[k] * W1[k * HH + tid];   // coalesced across tid
        }
        s_h[tid] = fmaxf(acc, 0.0f);
    }
    __syncthreads();

    // ---- Phase 3: logits[kk] = h . W2[:,kk] + b2[kk]
    if (tid < KK) {
        float acc = b2[tid];
        #pragma unroll 8
        for (int j = 0; j < HH; ++j) {
            acc += s_h[j] * W2[j * KK + tid];      // coalesced across tid
        }
        out[b * KK + tid] = acc;
    }
}

extern "C" void kernel_launch(void* const* d_in, const int* in_sizes, int n_in,
                              void* d_out, int out_size, void* d_ws, size_t ws_size,
                              hipStream_t stream) {
    const float* enc        = (const float*)d_in[0];
    const float* W1         = (const float*)d_in[1];
    const float* b1         = (const float*)d_in[2];
    const float* W2         = (const float*)d_in[3];
    const float* b2         = (const float*)d_in[4];
    const int*   valid_mask = (const int*)d_in[5];
    const int*   pos_span   = (const int*)d_in[6];
    // d_in[7] = mask_span: dead code in the reference output (mask_feat unused)
    float* out = (float*)d_out;

    halton_fused_kernel<<<BB, 768, 0, stream>>>(enc, W1, b1, W2, b2,
                                                valid_mask, pos_span, out);
}